// Round 5
// baseline (178.919 us; speedup 1.0000x reference)
//
#include <hip/hip_runtime.h>
#include <hip/hip_bf16.h>
#include <float.h>
#include <math.h>

// Problem constants: B=2, L=2048, D=1024, NH=16, HD=64
#define BB  2
#define LLEN 2048
#define DD  1024
#define NHH 16
#define HDD 64
#define MROWS (BB * LLEN)   // 4096

typedef __bf16 bf16x8  __attribute__((ext_vector_type(8)));
typedef float  f32x4   __attribute__((ext_vector_type(4)));
typedef float  f32x16  __attribute__((ext_vector_type(16)));

static __device__ __forceinline__ ushort f2bf(float f) {
    __hip_bfloat16 h = __float2bfloat16(f);
    return *reinterpret_cast<ushort*>(&h);
}

__device__ __forceinline__ void gload16(const void* g, void* l) {
    __builtin_amdgcn_global_load_lds(
        (const __attribute__((address_space(1))) void*)g,
        (__attribute__((address_space(3))) void*)l, 16, 0, 0);
}

// ---------------------------------------------------------------------------
// x fp32 -> bf16, 4 elems/thread
// ---------------------------------------------------------------------------
__global__ __launch_bounds__(256) void cvt_x_k(const float* __restrict__ in,
                                               ushort* __restrict__ out) {
    int idx = blockIdx.x * 256 + threadIdx.x;
    float4 v = reinterpret_cast<const float4*>(in)[idx];
    ushort4 o;
    o.x = f2bf(v.x); o.y = f2bf(v.y); o.z = f2bf(v.z); o.w = f2bf(v.w);
    reinterpret_cast<ushort4*>(out)[idx] = o;
}

// ---------------------------------------------------------------------------
// Weight transpose+convert: fp32 [1024][1024] -> bf16 [N][K]
// ---------------------------------------------------------------------------
__global__ __launch_bounds__(256) void wt_cvt_k(const float* __restrict__ in,
                                                ushort* __restrict__ out) {
    __shared__ float T[64][65];
    const int r0 = blockIdx.y * 64, c0 = blockIdx.x * 64;
    const int tid = threadIdx.x;
    for (int i = tid; i < 64 * 16; i += 256) {
        int r = i >> 4, c4 = (i & 15) * 4;
        float4 v = *reinterpret_cast<const float4*>(&in[(size_t)(r0 + r) * DD + c0 + c4]);
        T[r][c4 + 0] = v.x; T[r][c4 + 1] = v.y; T[r][c4 + 2] = v.z; T[r][c4 + 3] = v.w;
    }
    __syncthreads();
    for (int i = tid; i < 64 * 16; i += 256) {
        int rr = i >> 4, cc4 = (i & 15) * 4;
        ushort4 o;
        o.x = f2bf(T[cc4 + 0][rr]);
        o.y = f2bf(T[cc4 + 1][rr]);
        o.z = f2bf(T[cc4 + 2][rr]);
        o.w = f2bf(T[cc4 + 3][rr]);
        *reinterpret_cast<ushort4*>(&out[(size_t)(c0 + rr) * DD + r0 + cc4]) = o;
    }
}

// ---------------------------------------------------------------------------
// bf16 MFMA GEMM: C = A[M,K] @ Bt[N,K]^T + bias. 128x128 tile, BK=64.
// MODE 0: out fp32 [M][N]; MODE 1: N=3072 fused QKV scatter (bf16 per-head)
// ---------------------------------------------------------------------------
template <int MODE>
__global__ __launch_bounds__(256) void gemm_mfma_k(
    const __bf16* __restrict__ A, const __bf16* __restrict__ Bt,
    const float* __restrict__ bias0, const float* __restrict__ bias1,
    const float* __restrict__ bias2,
    float* __restrict__ out_f32,
    __hip_bfloat16* __restrict__ oq, __hip_bfloat16* __restrict__ ok,
    __hip_bfloat16* __restrict__ ov) {
    constexpr int K = DD;
    __shared__ __bf16 As[128 * 64];
    __shared__ __bf16 Bs[128 * 64];

    const int tid  = threadIdx.x;
    const int w    = tid >> 6;
    const int lane = tid & 63;
    const int lr   = lane & 15;
    const int lg   = lane >> 4;
    const int wr   = w >> 1, wc = w & 1;
    const int bm = blockIdx.y * 128, bn = blockIdx.x * 128;

    const int srow = lane >> 3;
    const int scol = ((lane & 7) ^ srow) * 8;
    const __bf16* gA = A  + (size_t)(bm + w * 32 + srow) * K + scol;
    const __bf16* gB = Bt + (size_t)(bn + w * 32 + srow) * K + scol;
    char* ldsA = (char*)As + w * 32 * 128;
    char* ldsB = (char*)Bs + w * 32 * 128;

    f32x4 acc[4][4] = {};

    const int l7 = lr & 7;
    for (int k0 = 0; k0 < K; k0 += 64) {
#pragma unroll
        for (int c = 0; c < 4; ++c) {
            gload16(gA + (size_t)(c * 8) * K + k0, ldsA + c * 1024);
            gload16(gB + (size_t)(c * 8) * K + k0, ldsB + c * 1024);
        }
        __syncthreads();
#pragma unroll
        for (int kk = 0; kk < 2; ++kk) {
            bf16x8 a[4], b[4];
#pragma unroll
            for (int m = 0; m < 4; ++m)
                a[m] = *reinterpret_cast<const bf16x8*>(
                    As + (wr * 64 + m * 16 + lr) * 64 + (((kk * 4 + lg) ^ l7) << 3));
#pragma unroll
            for (int n = 0; n < 4; ++n)
                b[n] = *reinterpret_cast<const bf16x8*>(
                    Bs + (wc * 64 + n * 16 + lr) * 64 + (((kk * 4 + lg) ^ l7) << 3));
#pragma unroll
            for (int m = 0; m < 4; ++m)
#pragma unroll
                for (int n = 0; n < 4; ++n)
                    acc[m][n] = __builtin_amdgcn_mfma_f32_16x16x32_bf16(a[m], b[n], acc[m][n], 0, 0, 0);
        }
        __syncthreads();
    }

    if (MODE == 1) {
        const int seg = bn >> 10;
        const float* biasp = (seg == 0) ? bias0 : (seg == 1 ? bias1 : bias2);
        __hip_bfloat16* segp = (seg == 0) ? oq : (seg == 1 ? ok : ov);
#pragma unroll
        for (int n = 0; n < 4; ++n) {
            const int gn = bn + wc * 64 + n * 16 + lr;
            const int nn = gn & 1023;
            const float bv = biasp[nn];
            const int h = nn >> 6, hd = nn & 63;
#pragma unroll
            for (int m = 0; m < 4; ++m)
#pragma unroll
                for (int i = 0; i < 4; ++i) {
                    const int row = bm + wr * 64 + m * 16 + lg * 4 + i;
                    const int b = row >> 11, l = row & (LLEN - 1);
                    segp[(((size_t)(b * NHH + h)) * LLEN + l) * HDD + hd] =
                        __float2bfloat16(acc[m][n][i] + bv);
                }
        }
    } else {
#pragma unroll
        for (int n = 0; n < 4; ++n) {
            const int gn = bn + wc * 64 + n * 16 + lr;
            const float bv = bias0[gn];
#pragma unroll
            for (int m = 0; m < 4; ++m)
#pragma unroll
                for (int i = 0; i < 4; ++i) {
                    const int row = bm + wr * 64 + m * 16 + lg * 4 + i;
                    out_f32[(size_t)row * DD + gn] = acc[m][n][i] + bv;
                }
        }
    }
}

// ---------------------------------------------------------------------------
// RoPE in-place on bf16 [BH][L][HD]; pairs (d, d+32)
// ---------------------------------------------------------------------------
__global__ __launch_bounds__(256) void rope16_k(__hip_bfloat16* __restrict__ T) {
    int idx = blockIdx.x * blockDim.x + threadIdx.x;
    int d = idx & 31;
    int l = (idx >> 5) & (LLEN - 1);
    int bh = idx >> 16;
    float ang = (float)l * __expf(-(float)d * 0.28782313662425572f);
    float s, c;
    __sincosf(ang, &s, &c);
    __hip_bfloat16* base = T + ((size_t)bh * LLEN + l) * HDD;
    float x1 = __bfloat162float(base[d]);
    float x2 = __bfloat162float(base[d + 32]);
    base[d]      = __float2bfloat16(x1 * c - x2 * s);
    base[d + 32] = __float2bfloat16(x2 * c + x1 * s);
}

// ---------------------------------------------------------------------------
// V transpose bf16: [BH][L][HD] -> [BH][HD][L]
// ---------------------------------------------------------------------------
__global__ __launch_bounds__(256) void vt16_k(const ushort* __restrict__ in,
                                              ushort* __restrict__ out) {
    __shared__ ushort T[64][72];
    const int bh = blockIdx.y;
    const int l0 = blockIdx.x * 64;
    const int tid = threadIdx.x;
    for (int i = tid; i < 64 * 16; i += 256) {
        int r = i >> 4, c4 = (i & 15) * 4;
        ushort4 v = *reinterpret_cast<const ushort4*>(&in[((size_t)bh * LLEN + l0 + r) * HDD + c4]);
        T[r][c4 + 0] = v.x; T[r][c4 + 1] = v.y; T[r][c4 + 2] = v.z; T[r][c4 + 3] = v.w;
    }
    __syncthreads();
    int d  = tid >> 2;
    int lc = (tid & 3) * 16;
    ushort* ob = out + ((size_t)bh * HDD + d) * LLEN + l0 + lc;
#pragma unroll
    for (int j = 0; j < 16; ++j) ob[j] = T[lc + j][d];
}

// ---------------------------------------------------------------------------
// Swapped-operand 32x32 MFMA flash attention (causal), ping-pong prefetch.
// 1D grid 512 blocks, XCD-swizzled so one head's 16 blocks share an XCD
// (K+V = 1 MB -> L2-resident). 4 waves/block; wave w owns q-tile w*16+bx.
// All K/V fragments prefetched one tile ahead into registers (no LDS).
// Softmax in exp2 domain (scale folds log2e). setprio around MFMA clusters.
// ---------------------------------------------------------------------------
#define ATTN_LOAD(KF, VF, T0)                                                   \
    do {                                                                        \
        const __bf16* kp_ = kbase + (size_t)(T0) * (32 * HDD);                  \
        KF[0] = *reinterpret_cast<const bf16x8*>(kp_);                          \
        KF[1] = *reinterpret_cast<const bf16x8*>(kp_ + 16);                     \
        KF[2] = *reinterpret_cast<const bf16x8*>(kp_ + 32);                     \
        KF[3] = *reinterpret_cast<const bf16x8*>(kp_ + 48);                     \
        const __bf16* vp_ = vbase + (T0) * 32;                                  \
        VF[0] = *reinterpret_cast<const bf16x8*>(vp_);                          \
        VF[1] = *reinterpret_cast<const bf16x8*>(vp_ + 16);                     \
        VF[2] = *reinterpret_cast<const bf16x8*>(vp_ + 32 * LLEN);              \
        VF[3] = *reinterpret_cast<const bf16x8*>(vp_ + 32 * LLEN + 16);         \
    } while (0)

#define ATTN_TILE(KF, VF, T0, MASKIT)                                           \
    do {                                                                        \
        f32x16 s_ = {};                                                         \
        __builtin_amdgcn_s_setprio(1);                                          \
        s_ = __builtin_amdgcn_mfma_f32_32x32x16_bf16(KF[0], qf[0], s_, 0, 0, 0);\
        s_ = __builtin_amdgcn_mfma_f32_32x32x16_bf16(KF[1], qf[1], s_, 0, 0, 0);\
        s_ = __builtin_amdgcn_mfma_f32_32x32x16_bf16(KF[2], qf[2], s_, 0, 0, 0);\
        s_ = __builtin_amdgcn_mfma_f32_32x32x16_bf16(KF[3], qf[3], s_, 0, 0, 0);\
        __builtin_amdgcn_s_setprio(0);                                          \
        float p_[16];                                                           \
        float pmax_ = -FLT_MAX;                                                 \
        const int k0_ = (T0) * 32;                                              \
        if (MASKIT) {                                                           \
            _Pragma("unroll")                                                   \
            for (int i = 0; i < 16; ++i) {                                      \
                int kkg_ = k0_ + (i & 3) + 8 * (i >> 2) + 4 * hi;               \
                float v_ = (kkg_ <= qg) ? s_[i] * SC2 : -FLT_MAX;               \
                p_[i] = v_; pmax_ = fmaxf(pmax_, v_);                           \
            }                                                                   \
        } else {                                                                \
            _Pragma("unroll")                                                   \
            for (int i = 0; i < 16; ++i) {                                      \
                float v_ = s_[i] * SC2;                                         \
                p_[i] = v_; pmax_ = fmaxf(pmax_, v_);                           \
            }                                                                   \
        }                                                                       \
        pmax_ = fmaxf(pmax_, __shfl_xor(pmax_, 32));                            \
        if (!__all(pmax_ <= m + 3.0f)) {                                        \
            float mnew_ = fmaxf(m, pmax_);                                      \
            float corr_ = exp2f(m - mnew_);                                     \
            m = mnew_;                                                          \
            lsum *= corr_;                                                      \
            _Pragma("unroll")                                                   \
            for (int i = 0; i < 16; ++i) { o0[i] *= corr_; o1[i] *= corr_; }    \
        }                                                                       \
        float ps_ = 0.f;                                                        \
        _Pragma("unroll")                                                       \
        for (int i = 0; i < 16; ++i) { p_[i] = exp2f(p_[i] - m); ps_ += p_[i]; }\
        ps_ += __shfl_xor(ps_, 32);                                             \
        lsum += ps_;                                                            \
        unsigned u_[8], x_[8];                                                  \
        _Pragma("unroll")                                                       \
        for (int j = 0; j < 8; ++j)                                             \
            u_[j] = (unsigned)f2bf(p_[2 * j]) | ((unsigned)f2bf(p_[2 * j + 1]) << 16); \
        _Pragma("unroll")                                                       \
        for (int j = 0; j < 8; ++j)                                             \
            x_[j] = (unsigned)__shfl_xor((int)u_[j], 32);                       \
        union { unsigned d[4]; bf16x8 v; } B1_, B2_;                            \
        if (hi == 0) {                                                          \
            B1_.d[0] = u_[0]; B1_.d[1] = u_[1]; B1_.d[2] = x_[0]; B1_.d[3] = x_[1]; \
            B2_.d[0] = u_[4]; B2_.d[1] = u_[5]; B2_.d[2] = x_[4]; B2_.d[3] = x_[5]; \
        } else {                                                                \
            B1_.d[0] = x_[2]; B1_.d[1] = x_[3]; B1_.d[2] = u_[2]; B1_.d[3] = u_[3]; \
            B2_.d[0] = x_[6]; B2_.d[1] = x_[7]; B2_.d[2] = u_[6]; B2_.d[3] = u_[7]; \
        }                                                                       \
        __builtin_amdgcn_s_setprio(1);                                          \
        o0 = __builtin_amdgcn_mfma_f32_32x32x16_bf16(VF[0], B1_.v, o0, 0, 0, 0);\
        o0 = __builtin_amdgcn_mfma_f32_32x32x16_bf16(VF[1], B2_.v, o0, 0, 0, 0);\
        o1 = __builtin_amdgcn_mfma_f32_32x32x16_bf16(VF[2], B1_.v, o1, 0, 0, 0);\
        o1 = __builtin_amdgcn_mfma_f32_32x32x16_bf16(VF[3], B2_.v, o1, 0, 0, 0);\
        __builtin_amdgcn_s_setprio(0);                                          \
    } while (0)

__global__ __launch_bounds__(256) void attn_mfma3_k(const __bf16* __restrict__ Q,
                                                    const __bf16* __restrict__ K,
                                                    const __bf16* __restrict__ Vt,
                                                    __hip_bfloat16* __restrict__ ctx) {
    constexpr float SC2 = 0.18033688011112042f;  // 0.125 * log2(e)

    const int tid  = threadIdx.x;
    const int w    = tid >> 6;
    const int lane = tid & 63;
    const int q32  = lane & 31;
    const int hi   = lane >> 5;

    // XCD swizzle: 512 blocks; chunk = (s%8)*64 + s/8 -> heads grouped per XCD
    const int s_   = blockIdx.x;
    const int chunk = (s_ & 7) * 64 + (s_ >> 3);
    const int bh   = chunk >> 4;
    const int bx   = chunk & 15;
    const int qtile = w * 16 + bx;  // 0..63
    const int qg   = qtile * 32 + q32;

    const __bf16* Qh = Q  + (size_t)bh * LLEN * HDD;
    const __bf16* Kh = K  + (size_t)bh * LLEN * HDD;
    const __bf16* Vh = Vt + (size_t)bh * HDD * LLEN;

    const __bf16* kbase = Kh + (size_t)q32 * HDD + hi * 8;
    const __bf16* vbase = Vh + (size_t)q32 * LLEN + hi * 8;

    // Q B-fragments (n=q), 4 d-steps of 16
    bf16x8 qf[4];
#pragma unroll
    for (int d = 0; d < 4; ++d)
        qf[d] = *reinterpret_cast<const bf16x8*>(Qh + (size_t)qg * HDD + d * 16 + hi * 8);

    f32x16 o0 = {}, o1 = {};
    float m = -FLT_MAX, lsum = 0.f;

    bf16x8 kA[4], vA[4], kB[4], vB[4];
    ATTN_LOAD(kA, vA, 0);
    int t = 0;
    while (true) {
        const bool lastA = (t == qtile);
        if (!lastA) ATTN_LOAD(kB, vB, t + 1);
        ATTN_TILE(kA, vA, t, lastA);
        if (lastA) break;
        ++t;
        const bool lastB = (t == qtile);
        if (!lastB) ATTN_LOAD(kA, vA, t + 1);
        ATTN_TILE(kB, vB, t, lastB);
        if (lastB) break;
        ++t;
    }

    // epilogue: O^T[d][q], lane col = q; write bf16 ctx [B][L][D]
    const float inv = 1.0f / lsum;
    const int b = bh >> 4, h = bh & 15;
    __hip_bfloat16* dst = ctx + ((size_t)(b * LLEN + qg)) * DD + h * HDD;
#pragma unroll
    for (int g = 0; g < 4; ++g) {
        int dbase = 8 * g + 4 * hi;
        ushort4 st;
        st.x = f2bf(o0[4 * g + 0] * inv);
        st.y = f2bf(o0[4 * g + 1] * inv);
        st.z = f2bf(o0[4 * g + 2] * inv);
        st.w = f2bf(o0[4 * g + 3] * inv);
        *reinterpret_cast<ushort4*>(dst + dbase) = st;
    }
#pragma unroll
    for (int g = 0; g < 4; ++g) {
        int dbase = 32 + 8 * g + 4 * hi;
        ushort4 st;
        st.x = f2bf(o1[4 * g + 0] * inv);
        st.y = f2bf(o1[4 * g + 1] * inv);
        st.z = f2bf(o1[4 * g + 2] * inv);
        st.w = f2bf(o1[4 * g + 3] * inv);
        *reinterpret_cast<ushort4*>(dst + dbase) = st;
    }
}

// ---------------------------------------------------------------------------
extern "C" void kernel_launch(void* const* d_in, const int* in_sizes, int n_in,
                              void* d_out, int out_size, void* d_ws, size_t ws_size,
                              hipStream_t stream) {
    const float* x    = (const float*)d_in[0];
    const float* wq_w = (const float*)d_in[1];
    const float* wq_b = (const float*)d_in[2];
    const float* wk_w = (const float*)d_in[3];
    const float* wk_b = (const float*)d_in[4];
    const float* wv_w = (const float*)d_in[5];
    const float* wv_b = (const float*)d_in[6];
    const float* wo_w = (const float*)d_in[7];
    const float* wo_b = (const float*)d_in[8];
    float* out = (float*)d_out;

    const size_t MB = 1024 * 1024;
    char* p = (char*)d_ws;
    __bf16* x16   = (__bf16*)p;            p += 8 * MB;
    __bf16* wqkvt = (__bf16*)p;            p += 6 * MB;
    __bf16* wot   = (__bf16*)p;            p += 2 * MB;
    __hip_bfloat16* q16  = (__hip_bfloat16*)p; p += 8 * MB;
    __hip_bfloat16* k16  = (__hip_bfloat16*)p; p += 8 * MB;
    __hip_bfloat16* v16  = (__hip_bfloat16*)p; p += 8 * MB;
    __hip_bfloat16* v16t = (__hip_bfloat16*)p; p += 8 * MB;
    __hip_bfloat16* ctx16 = (__hip_bfloat16*)p;

    hipLaunchKernelGGL(cvt_x_k, dim3(4096), dim3(256), 0, stream, x, (ushort*)x16);
    dim3 wtg(16, 16);
    hipLaunchKernelGGL(wt_cvt_k, wtg, dim3(256), 0, stream, wq_w, (ushort*)(wqkvt));
    hipLaunchKernelGGL(wt_cvt_k, wtg, dim3(256), 0, stream, wk_w, (ushort*)(wqkvt + (size_t)1024 * DD));
    hipLaunchKernelGGL(wt_cvt_k, wtg, dim3(256), 0, stream, wv_w, (ushort*)(wqkvt + (size_t)2048 * DD));
    hipLaunchKernelGGL(wt_cvt_k, wtg, dim3(256), 0, stream, wo_w, (ushort*)wot);

    hipLaunchKernelGGL((gemm_mfma_k<1>), dim3(24, 32), dim3(256), 0, stream,
                       x16, wqkvt, wq_b, wk_b, wv_b, (float*)nullptr, q16, k16, v16);

    int rope_threads = BB * NHH * LLEN * 32;
    hipLaunchKernelGGL(rope16_k, dim3(rope_threads / 256), dim3(256), 0, stream, q16);
    hipLaunchKernelGGL(rope16_k, dim3(rope_threads / 256), dim3(256), 0, stream, k16);

    hipLaunchKernelGGL(vt16_k, dim3(LLEN / 64, BB * NHH), dim3(256), 0, stream,
                       (const ushort*)v16, (ushort*)v16t);

    hipLaunchKernelGGL(attn_mfma3_k, dim3(512), dim3(256), 0, stream,
                       (const __bf16*)q16, (const __bf16*)k16, (const __bf16*)v16t, ctx16);

    hipLaunchKernelGGL((gemm_mfma_k<0>), dim3(8, 32), dim3(256), 0, stream,
                       (const __bf16*)ctx16, wot, wo_b, (const float*)nullptr, (const float*)nullptr,
                       out, (__hip_bfloat16*)nullptr, (__hip_bfloat16*)nullptr, (__hip_bfloat16*)nullptr);
}

// Round 6
// 152.213 us; speedup vs baseline: 1.1755x; 1.1755x over previous
//
#include <hip/hip_runtime.h>
#include <hip/hip_bf16.h>
#include <float.h>
#include <math.h>

// Problem constants: B=2, L=2048, D=1024, NH=16, HD=64
#define BB  2
#define LLEN 2048
#define DD  1024
#define NHH 16
#define HDD 64
#define MROWS (BB * LLEN)   // 4096

typedef __bf16 bf16x8  __attribute__((ext_vector_type(8)));
typedef float  f32x4   __attribute__((ext_vector_type(4)));
typedef float  f32x16  __attribute__((ext_vector_type(16)));

static __device__ __forceinline__ ushort f2bf(float f) {
    __hip_bfloat16 h = __float2bfloat16(f);
    return *reinterpret_cast<ushort*>(&h);
}

__device__ __forceinline__ void gload16(const void* g, void* l) {
    __builtin_amdgcn_global_load_lds(
        (const __attribute__((address_space(1))) void*)g,
        (__attribute__((address_space(3))) void*)l, 16, 0, 0);
}

// ---------------------------------------------------------------------------
// x fp32 -> bf16, 4 elems/thread
// ---------------------------------------------------------------------------
__global__ __launch_bounds__(256) void cvt_x_k(const float* __restrict__ in,
                                               ushort* __restrict__ out) {
    int idx = blockIdx.x * 256 + threadIdx.x;
    float4 v = reinterpret_cast<const float4*>(in)[idx];
    ushort4 o;
    o.x = f2bf(v.x); o.y = f2bf(v.y); o.z = f2bf(v.z); o.w = f2bf(v.w);
    reinterpret_cast<ushort4*>(out)[idx] = o;
}

// ---------------------------------------------------------------------------
// All 4 weight transposes+converts in one launch: fp32 [1024][1024] -> bf16 [N][K]
// z = 0,1,2 -> wqkvt segments; z = 3 -> wot
// ---------------------------------------------------------------------------
__global__ __launch_bounds__(256) void wt_cvt_all_k(const float* __restrict__ w0,
                                                    const float* __restrict__ w1,
                                                    const float* __restrict__ w2,
                                                    const float* __restrict__ w3,
                                                    ushort* __restrict__ qkv,
                                                    ushort* __restrict__ wo) {
    __shared__ float T[64][65];
    const int z = blockIdx.z;
    const float* in = (z == 0) ? w0 : (z == 1) ? w1 : (z == 2) ? w2 : w3;
    ushort* out = (z < 3) ? (qkv + (size_t)z * 1024 * DD) : wo;

    const int r0 = blockIdx.y * 64, c0 = blockIdx.x * 64;
    const int tid = threadIdx.x;
    for (int i = tid; i < 64 * 16; i += 256) {
        int r = i >> 4, c4 = (i & 15) * 4;
        float4 v = *reinterpret_cast<const float4*>(&in[(size_t)(r0 + r) * DD + c0 + c4]);
        T[r][c4 + 0] = v.x; T[r][c4 + 1] = v.y; T[r][c4 + 2] = v.z; T[r][c4 + 3] = v.w;
    }
    __syncthreads();
    for (int i = tid; i < 64 * 16; i += 256) {
        int rr = i >> 4, cc4 = (i & 15) * 4;
        ushort4 o;
        o.x = f2bf(T[cc4 + 0][rr]);
        o.y = f2bf(T[cc4 + 1][rr]);
        o.z = f2bf(T[cc4 + 2][rr]);
        o.w = f2bf(T[cc4 + 3][rr]);
        *reinterpret_cast<ushort4*>(&out[(size_t)(c0 + rr) * DD + r0 + cc4]) = o;
    }
}

// ---------------------------------------------------------------------------
// bf16 MFMA GEMM: C = A[M,K] @ Bt[N,K]^T + bias. 128x128 tile, BK=64.
// MODE 0: out fp32 [M][N]
// MODE 1: N=3072 fused QKV. seg 0/1 (Q,K): fused RoPE, store [BH][L][HD] bf16.
//         seg 2 (V): store transposed [BH][HD][L] bf16.
// RoPE fusion works because each wave's 64 cols = exactly one head, and the
// rotation pair (d, d+32) maps to acc cols (n2, n2+2) in the SAME thread.
// ---------------------------------------------------------------------------
template <int MODE>
__global__ __launch_bounds__(256) void gemm_mfma_k(
    const __bf16* __restrict__ A, const __bf16* __restrict__ Bt,
    const float* __restrict__ bias0, const float* __restrict__ bias1,
    const float* __restrict__ bias2,
    float* __restrict__ out_f32,
    __hip_bfloat16* __restrict__ oq, __hip_bfloat16* __restrict__ ok,
    __hip_bfloat16* __restrict__ ov) {
    constexpr int K = DD;
    __shared__ __bf16 As[128 * 64];
    __shared__ __bf16 Bs[128 * 64];

    const int tid  = threadIdx.x;
    const int w    = tid >> 6;
    const int lane = tid & 63;
    const int lr   = lane & 15;
    const int lg   = lane >> 4;
    const int wr   = w >> 1, wc = w & 1;
    const int bm = blockIdx.y * 128, bn = blockIdx.x * 128;

    const int srow = lane >> 3;
    const int scol = ((lane & 7) ^ srow) * 8;
    const __bf16* gA = A  + (size_t)(bm + w * 32 + srow) * K + scol;
    const __bf16* gB = Bt + (size_t)(bn + w * 32 + srow) * K + scol;
    char* ldsA = (char*)As + w * 32 * 128;
    char* ldsB = (char*)Bs + w * 32 * 128;

    f32x4 acc[4][4] = {};

    const int l7 = lr & 7;
    for (int k0 = 0; k0 < K; k0 += 64) {
#pragma unroll
        for (int c = 0; c < 4; ++c) {
            gload16(gA + (size_t)(c * 8) * K + k0, ldsA + c * 1024);
            gload16(gB + (size_t)(c * 8) * K + k0, ldsB + c * 1024);
        }
        __syncthreads();
#pragma unroll
        for (int kk = 0; kk < 2; ++kk) {
            bf16x8 a[4], b[4];
#pragma unroll
            for (int m = 0; m < 4; ++m)
                a[m] = *reinterpret_cast<const bf16x8*>(
                    As + (wr * 64 + m * 16 + lr) * 64 + (((kk * 4 + lg) ^ l7) << 3));
#pragma unroll
            for (int n = 0; n < 4; ++n)
                b[n] = *reinterpret_cast<const bf16x8*>(
                    Bs + (wc * 64 + n * 16 + lr) * 64 + (((kk * 4 + lg) ^ l7) << 3));
#pragma unroll
            for (int m = 0; m < 4; ++m)
#pragma unroll
                for (int n = 0; n < 4; ++n)
                    acc[m][n] = __builtin_amdgcn_mfma_f32_16x16x32_bf16(a[m], b[n], acc[m][n], 0, 0, 0);
        }
        __syncthreads();
    }

    if (MODE == 1) {
        const int seg = bn >> 10;                     // 0=Q,1=K,2=V
        const int colbase = (bn & 1023) + wc * 64;    // head-col base (mult of 64)
        const int h = colbase >> 6;
        if (seg == 2) {
            // V: bias + transposed store [BH][HD][L], 4 l's per ushort4
#pragma unroll
            for (int n = 0; n < 4; ++n) {
                const int hd = n * 16 + lr;
                const float bv = bias2[colbase + hd];
#pragma unroll
                for (int m = 0; m < 4; ++m) {
                    const int rowb = bm + wr * 64 + m * 16 + lg * 4;
                    const int b = rowb >> 11, l0 = rowb & (LLEN - 1);
                    ushort4 st;
                    st.x = f2bf(acc[m][n][0] + bv);
                    st.y = f2bf(acc[m][n][1] + bv);
                    st.z = f2bf(acc[m][n][2] + bv);
                    st.w = f2bf(acc[m][n][3] + bv);
                    *reinterpret_cast<ushort4*>(
                        &ov[((size_t)(b * NHH + h) * HDD + hd) * LLEN + l0]) =
                        *reinterpret_cast<ushort4*>(&st);
                }
            }
        } else {
            __hip_bfloat16* segp = (seg == 0) ? oq : ok;
            const float* biasp   = (seg == 0) ? bias0 : bias1;
#pragma unroll
            for (int n2 = 0; n2 < 2; ++n2) {
                const int d = n2 * 16 + lr;                       // 0..31
                const float tsd = exp2f((float)d * -0.4152410118609203f);  // 1e4^(-d/32)
                const float bv0 = biasp[colbase + d];
                const float bv1 = biasp[colbase + d + 32];
#pragma unroll
                for (int m = 0; m < 4; ++m) {
                    const int rowb = bm + wr * 64 + m * 16 + lg * 4;
                    const int b = rowb >> 11, lb = rowb & (LLEN - 1);
#pragma unroll
                    for (int i = 0; i < 4; ++i) {
                        const int l = lb + i;
                        float s, c;
                        __sincosf((float)l * tsd, &s, &c);
                        const float x0 = acc[m][n2][i] + bv0;
                        const float x1 = acc[m][n2 + 2][i] + bv1;
                        __hip_bfloat16* pb =
                            segp + ((size_t)(b * NHH + h) * LLEN + l) * HDD;
                        pb[d]      = __float2bfloat16(x0 * c - x1 * s);
                        pb[d + 32] = __float2bfloat16(x1 * c + x0 * s);
                    }
                }
            }
        }
    } else {
#pragma unroll
        for (int n = 0; n < 4; ++n) {
            const int gn = bn + wc * 64 + n * 16 + lr;
            const float bv = bias0[gn];
#pragma unroll
            for (int m = 0; m < 4; ++m)
#pragma unroll
                for (int i = 0; i < 4; ++i) {
                    const int row = bm + wr * 64 + m * 16 + lg * 4 + i;
                    out_f32[(size_t)row * DD + gn] = acc[m][n][i] + bv;
                }
        }
    }
}

// ---------------------------------------------------------------------------
// Swapped-operand 32x32 MFMA flash attention (causal), 4-way split-KV.
// Grid 2048 blocks (one per head x q-tile, XCD-swizzled, heavy tiles first).
// 4 waves/block; wave w processes kv tiles t = w, w+4, ... (mod-4 interleave),
// keeping partial (o, m, lsum); merge via LDS (+1 barrier); wave w writes
// output reg-quarter w. Ping-pong register prefetch of next tile's K/V.
// ---------------------------------------------------------------------------
#define ATTN_LOAD(KF, VF, T0)                                                   \
    do {                                                                        \
        const __bf16* kp_ = kbase + (size_t)(T0) * (32 * HDD);                  \
        KF[0] = *reinterpret_cast<const bf16x8*>(kp_);                          \
        KF[1] = *reinterpret_cast<const bf16x8*>(kp_ + 16);                     \
        KF[2] = *reinterpret_cast<const bf16x8*>(kp_ + 32);                     \
        KF[3] = *reinterpret_cast<const bf16x8*>(kp_ + 48);                     \
        const __bf16* vp_ = vbase + (T0) * 32;                                  \
        VF[0] = *reinterpret_cast<const bf16x8*>(vp_);                          \
        VF[1] = *reinterpret_cast<const bf16x8*>(vp_ + 16);                     \
        VF[2] = *reinterpret_cast<const bf16x8*>(vp_ + 32 * LLEN);              \
        VF[3] = *reinterpret_cast<const bf16x8*>(vp_ + 32 * LLEN + 16);         \
    } while (0)

#define ATTN_TILE(KF, VF, T0, MASKIT)                                           \
    do {                                                                        \
        f32x16 s_ = {};                                                         \
        __builtin_amdgcn_s_setprio(1);                                          \
        s_ = __builtin_amdgcn_mfma_f32_32x32x16_bf16(KF[0], qf[0], s_, 0, 0, 0);\
        s_ = __builtin_amdgcn_mfma_f32_32x32x16_bf16(KF[1], qf[1], s_, 0, 0, 0);\
        s_ = __builtin_amdgcn_mfma_f32_32x32x16_bf16(KF[2], qf[2], s_, 0, 0, 0);\
        s_ = __builtin_amdgcn_mfma_f32_32x32x16_bf16(KF[3], qf[3], s_, 0, 0, 0);\
        __builtin_amdgcn_s_setprio(0);                                          \
        float p_[16];                                                           \
        float pmax_ = -FLT_MAX;                                                 \
        const int k0_ = (T0) * 32;                                              \
        if (MASKIT) {                                                           \
            _Pragma("unroll")                                                   \
            for (int i = 0; i < 16; ++i) {                                      \
                int kkg_ = k0_ + (i & 3) + 8 * (i >> 2) + 4 * hi;               \
                float v_ = (kkg_ <= qg) ? s_[i] * SC2 : -FLT_MAX;               \
                p_[i] = v_; pmax_ = fmaxf(pmax_, v_);                           \
            }                                                                   \
        } else {                                                                \
            _Pragma("unroll")                                                   \
            for (int i = 0; i < 16; ++i) {                                      \
                float v_ = s_[i] * SC2;                                         \
                p_[i] = v_; pmax_ = fmaxf(pmax_, v_);                           \
            }                                                                   \
        }                                                                       \
        pmax_ = fmaxf(pmax_, __shfl_xor(pmax_, 32));                            \
        if (!__all(pmax_ <= m + 3.0f)) {                                        \
            float mnew_ = fmaxf(m, pmax_);                                      \
            float corr_ = exp2f(m - mnew_);                                     \
            m = mnew_;                                                          \
            lsum *= corr_;                                                      \
            _Pragma("unroll")                                                   \
            for (int i = 0; i < 16; ++i) { o0[i] *= corr_; o1[i] *= corr_; }    \
        }                                                                       \
        float ps_ = 0.f;                                                        \
        _Pragma("unroll")                                                       \
        for (int i = 0; i < 16; ++i) { p_[i] = exp2f(p_[i] - m); ps_ += p_[i]; }\
        ps_ += __shfl_xor(ps_, 32);                                             \
        lsum += ps_;                                                            \
        unsigned u_[8], x_[8];                                                  \
        _Pragma("unroll")                                                       \
        for (int j = 0; j < 8; ++j)                                             \
            u_[j] = (unsigned)f2bf(p_[2 * j]) | ((unsigned)f2bf(p_[2 * j + 1]) << 16); \
        _Pragma("unroll")                                                       \
        for (int j = 0; j < 8; ++j)                                             \
            x_[j] = (unsigned)__shfl_xor((int)u_[j], 32);                       \
        union { unsigned d[4]; bf16x8 v; } B1_, B2_;                            \
        if (hi == 0) {                                                          \
            B1_.d[0] = u_[0]; B1_.d[1] = u_[1]; B1_.d[2] = x_[0]; B1_.d[3] = x_[1]; \
            B2_.d[0] = u_[4]; B2_.d[1] = u_[5]; B2_.d[2] = x_[4]; B2_.d[3] = x_[5]; \
        } else {                                                                \
            B1_.d[0] = x_[2]; B1_.d[1] = x_[3]; B1_.d[2] = u_[2]; B1_.d[3] = u_[3]; \
            B2_.d[0] = x_[6]; B2_.d[1] = x_[7]; B2_.d[2] = u_[6]; B2_.d[3] = u_[7]; \
        }                                                                       \
        __builtin_amdgcn_s_setprio(1);                                          \
        o0 = __builtin_amdgcn_mfma_f32_32x32x16_bf16(VF[0], B1_.v, o0, 0, 0, 0);\
        o0 = __builtin_amdgcn_mfma_f32_32x32x16_bf16(VF[1], B2_.v, o0, 0, 0, 0);\
        o1 = __builtin_amdgcn_mfma_f32_32x32x16_bf16(VF[2], B1_.v, o1, 0, 0, 0);\
        o1 = __builtin_amdgcn_mfma_f32_32x32x16_bf16(VF[3], B2_.v, o1, 0, 0, 0);\
        __builtin_amdgcn_s_setprio(0);                                          \
    } while (0)

__global__ __launch_bounds__(256) void attn_mfma4_k(const __bf16* __restrict__ Q,
                                                    const __bf16* __restrict__ K,
                                                    const __bf16* __restrict__ Vt,
                                                    __hip_bfloat16* __restrict__ ctx) {
    constexpr float SC2 = 0.18033688011112042f;  // 0.125 * log2(e)

    __shared__ float oL[4][64][33];  // pad 33: (lane+r)%32 -> 2-way (free)
    __shared__ float mvL[4][64];
    __shared__ float lvL[4][64];

    const int tid  = threadIdx.x;
    const int w    = tid >> 6;
    const int lane = tid & 63;
    const int q32  = lane & 31;
    const int hi   = lane >> 5;

    // XCD swizzle: consecutive-swz blocks on one XCD; 4 heads per XCD.
    const int bid = blockIdx.x;                      // 0..2047
    const int swz = (bid & 7) * 256 + (bid >> 3);
    const int bh  = swz >> 6;
    const int qtile = 63 - (swz & 63);               // heavy q-tiles first
    const int qg  = qtile * 32 + q32;

    const __bf16* Qh = Q  + (size_t)bh * LLEN * HDD;
    const __bf16* Kh = K  + (size_t)bh * LLEN * HDD;
    const __bf16* Vh = Vt + (size_t)bh * HDD * LLEN;

    const __bf16* kbase = Kh + (size_t)q32 * HDD + hi * 8;
    const __bf16* vbase = Vh + (size_t)q32 * LLEN + hi * 8;

    bf16x8 qf[4];
#pragma unroll
    for (int d = 0; d < 4; ++d)
        qf[d] = *reinterpret_cast<const bf16x8*>(Qh + (size_t)qg * HDD + d * 16 + hi * 8);

    f32x16 o0 = {}, o1 = {};
    float m = -FLT_MAX, lsum = 0.f;

    bf16x8 kA[4], vA[4], kB[4], vB[4];
    int t = w;
    if (t <= qtile) {
        ATTN_LOAD(kA, vA, t);
        while (true) {
            bool last = (t + 4 > qtile);
            if (!last) ATTN_LOAD(kB, vB, t + 4);
            ATTN_TILE(kA, vA, t, t == qtile);
            if (last) break;
            t += 4;
            last = (t + 4 > qtile);
            if (!last) ATTN_LOAD(kA, vA, t + 4);
            ATTN_TILE(kB, vB, t, t == qtile);
            if (last) break;
            t += 4;
        }
    }

    // write partials
#pragma unroll
    for (int r = 0; r < 16; ++r) {
        oL[w][lane][r]      = o0[r];
        oL[w][lane][16 + r] = o1[r];
    }
    mvL[w][lane] = m;
    lvL[w][lane] = lsum;
    __syncthreads();

    // merge: wave w handles output regs [w*8, w*8+8)
    float mj[4], lj[4];
#pragma unroll
    for (int j = 0; j < 4; ++j) { mj[j] = mvL[j][lane]; lj[j] = lvL[j][lane]; }
    float mstar = fmaxf(fmaxf(mj[0], mj[1]), fmaxf(mj[2], mj[3]));
    float sj[4];
    float Lt = 0.f;
#pragma unroll
    for (int j = 0; j < 4; ++j) {
        sj[j] = (lj[j] > 0.f) ? exp2f(mj[j] - mstar) : 0.f;
        Lt += lj[j] * sj[j];
    }
    const float inv = 1.0f / Lt;

    const int b = bh >> 4, h = bh & 15;
    __hip_bfloat16* dst = ctx + ((size_t)(b * LLEN + qg)) * DD + h * HDD;
    const int T = w >> 1;            // 0 -> o0 regs, 1 -> o1 regs
    const int gb = (w & 1) * 2;
#pragma unroll
    for (int g2 = 0; g2 < 2; ++g2) {
        const int g = gb + g2;
        ushort st4[4];
#pragma unroll
        for (int e = 0; e < 4; ++e) {
            const int r = T * 16 + 4 * g + e;
            float val = oL[0][lane][r] * sj[0] + oL[1][lane][r] * sj[1] +
                        oL[2][lane][r] * sj[2] + oL[3][lane][r] * sj[3];
            st4[e] = f2bf(val * inv);
        }
        const int d = T * 32 + 8 * g + 4 * hi;
        *reinterpret_cast<ushort4*>(dst + d) =
            *reinterpret_cast<ushort4*>(st4);
    }
}

// ---------------------------------------------------------------------------
extern "C" void kernel_launch(void* const* d_in, const int* in_sizes, int n_in,
                              void* d_out, int out_size, void* d_ws, size_t ws_size,
                              hipStream_t stream) {
    const float* x    = (const float*)d_in[0];
    const float* wq_w = (const float*)d_in[1];
    const float* wq_b = (const float*)d_in[2];
    const float* wk_w = (const float*)d_in[3];
    const float* wk_b = (const float*)d_in[4];
    const float* wv_w = (const float*)d_in[5];
    const float* wv_b = (const float*)d_in[6];
    const float* wo_w = (const float*)d_in[7];
    const float* wo_b = (const float*)d_in[8];
    float* out = (float*)d_out;

    const size_t MB = 1024 * 1024;
    char* p = (char*)d_ws;
    __bf16* x16   = (__bf16*)p;            p += 8 * MB;   // [4096][1024]
    __bf16* wqkvt = (__bf16*)p;            p += 6 * MB;   // [3072][1024]
    __bf16* wot   = (__bf16*)p;            p += 2 * MB;   // [1024][1024]
    __hip_bfloat16* q16  = (__hip_bfloat16*)p; p += 8 * MB;  // [BH][L][HD]
    __hip_bfloat16* k16  = (__hip_bfloat16*)p; p += 8 * MB;  // [BH][L][HD]
    __hip_bfloat16* v16t = (__hip_bfloat16*)p; p += 8 * MB;  // [BH][HD][L]
    __hip_bfloat16* ctx16 = (__hip_bfloat16*)p;               // [B][L][D]

    hipLaunchKernelGGL(cvt_x_k, dim3(4096), dim3(256), 0, stream, x, (ushort*)x16);
    hipLaunchKernelGGL(wt_cvt_all_k, dim3(16, 16, 4), dim3(256), 0, stream,
                       wq_w, wk_w, wv_w, wo_w, (ushort*)wqkvt, (ushort*)wot);

    // fused QKV projection + RoPE (Q,K) + V transpose
    hipLaunchKernelGGL((gemm_mfma_k<1>), dim3(24, 32), dim3(256), 0, stream,
                       x16, wqkvt, wq_b, wk_b, wv_b, (float*)nullptr, q16, k16, v16t);

    // attention (4-way split-KV)
    hipLaunchKernelGGL(attn_mfma4_k, dim3(2048), dim3(256), 0, stream,
                       (const __bf16*)q16, (const __bf16*)k16, (const __bf16*)v16t, ctx16);

    // output projection
    hipLaunchKernelGGL((gemm_mfma_k<0>), dim3(8, 32), dim3(256), 0, stream,
                       (const __bf16*)ctx16, wot, wo_b, (const float*)nullptr, (const float*)nullptr,
                       out, (__hip_bfloat16*)nullptr, (__hip_bfloat16*)nullptr, (__hip_bfloat16*)nullptr);
}

// Round 7
// 142.155 us; speedup vs baseline: 1.2586x; 1.0708x over previous
//
#include <hip/hip_runtime.h>
#include <hip/hip_bf16.h>
#include <float.h>
#include <math.h>

// Problem constants: B=2, L=2048, D=1024, NH=16, HD=64
#define BB  2
#define LLEN 2048
#define DD  1024
#define NHH 16
#define HDD 64
#define MROWS (BB * LLEN)   // 4096

typedef __bf16 bf16x8  __attribute__((ext_vector_type(8)));
typedef float  f32x4   __attribute__((ext_vector_type(4)));
typedef float  f32x16  __attribute__((ext_vector_type(16)));

static __device__ __forceinline__ ushort f2bf(float f) {
    __hip_bfloat16 h = __float2bfloat16(f);
    return *reinterpret_cast<ushort*>(&h);
}

__device__ __forceinline__ void gload16(const void* g, void* l) {
    __builtin_amdgcn_global_load_lds(
        (const __attribute__((address_space(1))) void*)g,
        (__attribute__((address_space(3))) void*)l, 16, 0, 0);
}

// ---------------------------------------------------------------------------
// x fp32 -> bf16, 4 elems/thread
// ---------------------------------------------------------------------------
__global__ __launch_bounds__(256) void cvt_x_k(const float* __restrict__ in,
                                               ushort* __restrict__ out) {
    int idx = blockIdx.x * 256 + threadIdx.x;
    float4 v = reinterpret_cast<const float4*>(in)[idx];
    ushort4 o;
    o.x = f2bf(v.x); o.y = f2bf(v.y); o.z = f2bf(v.z); o.w = f2bf(v.w);
    reinterpret_cast<ushort4*>(out)[idx] = o;
}

// ---------------------------------------------------------------------------
// All 4 weight transposes+converts in one launch: fp32 [1024][1024] -> bf16 [N][K]
// z = 0,1,2 -> wqkvt segments; z = 3 -> wot
// ---------------------------------------------------------------------------
__global__ __launch_bounds__(256) void wt_cvt_all_k(const float* __restrict__ w0,
                                                    const float* __restrict__ w1,
                                                    const float* __restrict__ w2,
                                                    const float* __restrict__ w3,
                                                    ushort* __restrict__ qkv,
                                                    ushort* __restrict__ wo) {
    __shared__ float T[64][65];
    const int z = blockIdx.z;
    const float* in = (z == 0) ? w0 : (z == 1) ? w1 : (z == 2) ? w2 : w3;
    ushort* out = (z < 3) ? (qkv + (size_t)z * 1024 * DD) : wo;

    const int r0 = blockIdx.y * 64, c0 = blockIdx.x * 64;
    const int tid = threadIdx.x;
    for (int i = tid; i < 64 * 16; i += 256) {
        int r = i >> 4, c4 = (i & 15) * 4;
        float4 v = *reinterpret_cast<const float4*>(&in[(size_t)(r0 + r) * DD + c0 + c4]);
        T[r][c4 + 0] = v.x; T[r][c4 + 1] = v.y; T[r][c4 + 2] = v.z; T[r][c4 + 3] = v.w;
    }
    __syncthreads();
    for (int i = tid; i < 64 * 16; i += 256) {
        int rr = i >> 4, cc4 = (i & 15) * 4;
        ushort4 o;
        o.x = f2bf(T[cc4 + 0][rr]);
        o.y = f2bf(T[cc4 + 1][rr]);
        o.z = f2bf(T[cc4 + 2][rr]);
        o.w = f2bf(T[cc4 + 3][rr]);
        *reinterpret_cast<ushort4*>(&out[(size_t)(c0 + rr) * DD + r0 + cc4]) = o;
    }
}

// ---------------------------------------------------------------------------
// bf16 MFMA GEMM: C = A[M,K] @ Bt[N,K]^T + bias. 128x128 tile, BK=64.
// MODE 0: out fp32 [M][N]
// MODE 1: N=3072 fused QKV. seg 0/1 (Q,K): fused RoPE, store [BH][L][HD] bf16;
//         Q additionally pre-scaled by SC2 = 0.125*log2(e) (softmax fold).
//         seg 2 (V): store transposed [BH][HD][L] bf16.
// ---------------------------------------------------------------------------
template <int MODE>
__global__ __launch_bounds__(256) void gemm_mfma_k(
    const __bf16* __restrict__ A, const __bf16* __restrict__ Bt,
    const float* __restrict__ bias0, const float* __restrict__ bias1,
    const float* __restrict__ bias2,
    float* __restrict__ out_f32,
    __hip_bfloat16* __restrict__ oq, __hip_bfloat16* __restrict__ ok,
    __hip_bfloat16* __restrict__ ov) {
    constexpr int K = DD;
    __shared__ __bf16 As[128 * 64];
    __shared__ __bf16 Bs[128 * 64];

    const int tid  = threadIdx.x;
    const int w    = tid >> 6;
    const int lane = tid & 63;
    const int lr   = lane & 15;
    const int lg   = lane >> 4;
    const int wr   = w >> 1, wc = w & 1;
    const int bm = blockIdx.y * 128, bn = blockIdx.x * 128;

    const int srow = lane >> 3;
    const int scol = ((lane & 7) ^ srow) * 8;
    const __bf16* gA = A  + (size_t)(bm + w * 32 + srow) * K + scol;
    const __bf16* gB = Bt + (size_t)(bn + w * 32 + srow) * K + scol;
    char* ldsA = (char*)As + w * 32 * 128;
    char* ldsB = (char*)Bs + w * 32 * 128;

    f32x4 acc[4][4] = {};

    const int l7 = lr & 7;
    for (int k0 = 0; k0 < K; k0 += 64) {
#pragma unroll
        for (int c = 0; c < 4; ++c) {
            gload16(gA + (size_t)(c * 8) * K + k0, ldsA + c * 1024);
            gload16(gB + (size_t)(c * 8) * K + k0, ldsB + c * 1024);
        }
        __syncthreads();
#pragma unroll
        for (int kk = 0; kk < 2; ++kk) {
            bf16x8 a[4], b[4];
#pragma unroll
            for (int m = 0; m < 4; ++m)
                a[m] = *reinterpret_cast<const bf16x8*>(
                    As + (wr * 64 + m * 16 + lr) * 64 + (((kk * 4 + lg) ^ l7) << 3));
#pragma unroll
            for (int n = 0; n < 4; ++n)
                b[n] = *reinterpret_cast<const bf16x8*>(
                    Bs + (wc * 64 + n * 16 + lr) * 64 + (((kk * 4 + lg) ^ l7) << 3));
#pragma unroll
            for (int m = 0; m < 4; ++m)
#pragma unroll
                for (int n = 0; n < 4; ++n)
                    acc[m][n] = __builtin_amdgcn_mfma_f32_16x16x32_bf16(a[m], b[n], acc[m][n], 0, 0, 0);
        }
        __syncthreads();
    }

    if (MODE == 1) {
        const int seg = bn >> 10;                     // 0=Q,1=K,2=V
        const int colbase = (bn & 1023) + wc * 64;    // head-col base (mult of 64)
        const int h = colbase >> 6;
        if (seg == 2) {
#pragma unroll
            for (int n = 0; n < 4; ++n) {
                const int hd = n * 16 + lr;
                const float bv = bias2[colbase + hd];
#pragma unroll
                for (int m = 0; m < 4; ++m) {
                    const int rowb = bm + wr * 64 + m * 16 + lg * 4;
                    const int b = rowb >> 11, l0 = rowb & (LLEN - 1);
                    ushort4 st;
                    st.x = f2bf(acc[m][n][0] + bv);
                    st.y = f2bf(acc[m][n][1] + bv);
                    st.z = f2bf(acc[m][n][2] + bv);
                    st.w = f2bf(acc[m][n][3] + bv);
                    *reinterpret_cast<ushort4*>(
                        &ov[((size_t)(b * NHH + h) * HDD + hd) * LLEN + l0]) =
                        *reinterpret_cast<ushort4*>(&st);
                }
            }
        } else {
            __hip_bfloat16* segp = (seg == 0) ? oq : ok;
            const float* biasp   = (seg == 0) ? bias0 : bias1;
            const float osc = (seg == 0) ? 0.18033688011112042f : 1.0f;  // SC2 fold
#pragma unroll
            for (int n2 = 0; n2 < 2; ++n2) {
                const int d = n2 * 16 + lr;                       // 0..31
                const float tsd = exp2f((float)d * -0.4152410118609203f);  // 1e4^(-d/32)
                const float bv0 = biasp[colbase + d];
                const float bv1 = biasp[colbase + d + 32];
#pragma unroll
                for (int m = 0; m < 4; ++m) {
                    const int rowb = bm + wr * 64 + m * 16 + lg * 4;
                    const int b = rowb >> 11, lb = rowb & (LLEN - 1);
#pragma unroll
                    for (int i = 0; i < 4; ++i) {
                        const int l = lb + i;
                        float s, c;
                        __sincosf((float)l * tsd, &s, &c);
                        const float x0 = acc[m][n2][i] + bv0;
                        const float x1 = acc[m][n2 + 2][i] + bv1;
                        __hip_bfloat16* pb =
                            segp + ((size_t)(b * NHH + h) * LLEN + l) * HDD;
                        pb[d]      = __float2bfloat16((x0 * c - x1 * s) * osc);
                        pb[d + 32] = __float2bfloat16((x1 * c + x0 * s) * osc);
                    }
                }
            }
        }
    } else {
#pragma unroll
        for (int n = 0; n < 4; ++n) {
            const int gn = bn + wc * 64 + n * 16 + lr;
            const float bv = bias0[gn];
#pragma unroll
            for (int m = 0; m < 4; ++m)
#pragma unroll
                for (int i = 0; i < 4; ++i) {
                    const int row = bm + wr * 64 + m * 16 + lg * 4 + i;
                    out_f32[(size_t)row * DD + gn] = acc[m][n][i] + bv;
                }
        }
    }
}

// ---------------------------------------------------------------------------
// Paired-qtile sequential flash attention (causal), swapped-operand 32x32 MFMA.
// Grid 1024 blocks = 32 heads x 32 pairs (XCD-swizzled). 4 waves/block.
// Block handles qtiles (63-ap) then (ap): per-wave work = 16.25 tiles exactly
// (uniform across ALL waves of the grid -> no tail). Wave w takes kv tiles
// t = w, w+4, ...; 4-way partial (o,m,lsum); LDS merge reused across phases.
// Q pre-scaled by SC2 -> softmax operates directly in log2 domain.
// ---------------------------------------------------------------------------
#define ATTN_LOAD(KF, VF, T0)                                                   \
    do {                                                                        \
        const __bf16* kp_ = kbase + (size_t)(T0) * (32 * HDD);                  \
        KF[0] = *reinterpret_cast<const bf16x8*>(kp_);                          \
        KF[1] = *reinterpret_cast<const bf16x8*>(kp_ + 16);                     \
        KF[2] = *reinterpret_cast<const bf16x8*>(kp_ + 32);                     \
        KF[3] = *reinterpret_cast<const bf16x8*>(kp_ + 48);                     \
        const __bf16* vp_ = vbase + (T0) * 32;                                  \
        VF[0] = *reinterpret_cast<const bf16x8*>(vp_);                          \
        VF[1] = *reinterpret_cast<const bf16x8*>(vp_ + 16);                     \
        VF[2] = *reinterpret_cast<const bf16x8*>(vp_ + 32 * LLEN);              \
        VF[3] = *reinterpret_cast<const bf16x8*>(vp_ + 32 * LLEN + 16);         \
    } while (0)

#define ATTN_TILE(KF, VF, T0, MASKIT, QG)                                       \
    do {                                                                        \
        f32x16 s_ = {};                                                         \
        __builtin_amdgcn_s_setprio(1);                                          \
        s_ = __builtin_amdgcn_mfma_f32_32x32x16_bf16(KF[0], qf[0], s_, 0, 0, 0);\
        s_ = __builtin_amdgcn_mfma_f32_32x32x16_bf16(KF[1], qf[1], s_, 0, 0, 0);\
        s_ = __builtin_amdgcn_mfma_f32_32x32x16_bf16(KF[2], qf[2], s_, 0, 0, 0);\
        s_ = __builtin_amdgcn_mfma_f32_32x32x16_bf16(KF[3], qf[3], s_, 0, 0, 0);\
        __builtin_amdgcn_s_setprio(0);                                          \
        float p_[16];                                                           \
        float pmax_ = -FLT_MAX;                                                 \
        const int k0_ = (T0) * 32;                                              \
        if (MASKIT) {                                                           \
            _Pragma("unroll")                                                   \
            for (int i = 0; i < 16; ++i) {                                      \
                int kkg_ = k0_ + (i & 3) + 8 * (i >> 2) + 4 * hi;               \
                float v_ = (kkg_ <= (QG)) ? s_[i] : -FLT_MAX;                   \
                p_[i] = v_; pmax_ = fmaxf(pmax_, v_);                           \
            }                                                                   \
        } else {                                                                \
            _Pragma("unroll")                                                   \
            for (int i = 0; i < 16; ++i) {                                      \
                p_[i] = s_[i]; pmax_ = fmaxf(pmax_, s_[i]);                     \
            }                                                                   \
        }                                                                       \
        pmax_ = fmaxf(pmax_, __shfl_xor(pmax_, 32));                            \
        if (!__all(pmax_ <= m + 3.0f)) {                                        \
            float mnew_ = fmaxf(m, pmax_);                                      \
            float corr_ = exp2f(m - mnew_);                                     \
            m = mnew_;                                                          \
            lsum *= corr_;                                                      \
            _Pragma("unroll")                                                   \
            for (int i = 0; i < 16; ++i) { o0[i] *= corr_; o1[i] *= corr_; }    \
        }                                                                       \
        float ps_ = 0.f;                                                        \
        _Pragma("unroll")                                                       \
        for (int i = 0; i < 16; ++i) { p_[i] = exp2f(p_[i] - m); ps_ += p_[i]; }\
        ps_ += __shfl_xor(ps_, 32);                                             \
        lsum += ps_;                                                            \
        unsigned u_[8], x_[8];                                                  \
        _Pragma("unroll")                                                       \
        for (int j = 0; j < 8; ++j)                                             \
            u_[j] = (unsigned)f2bf(p_[2 * j]) | ((unsigned)f2bf(p_[2 * j + 1]) << 16); \
        _Pragma("unroll")                                                       \
        for (int j = 0; j < 8; ++j)                                             \
            x_[j] = (unsigned)__shfl_xor((int)u_[j], 32);                       \
        union { unsigned d[4]; bf16x8 v; } B1_, B2_;                            \
        if (hi == 0) {                                                          \
            B1_.d[0] = u_[0]; B1_.d[1] = u_[1]; B1_.d[2] = x_[0]; B1_.d[3] = x_[1]; \
            B2_.d[0] = u_[4]; B2_.d[1] = u_[5]; B2_.d[2] = x_[4]; B2_.d[3] = x_[5]; \
        } else {                                                                \
            B1_.d[0] = x_[2]; B1_.d[1] = x_[3]; B1_.d[2] = u_[2]; B1_.d[3] = u_[3]; \
            B2_.d[0] = x_[6]; B2_.d[1] = x_[7]; B2_.d[2] = u_[6]; B2_.d[3] = u_[7]; \
        }                                                                       \
        __builtin_amdgcn_s_setprio(1);                                          \
        o0 = __builtin_amdgcn_mfma_f32_32x32x16_bf16(VF[0], B1_.v, o0, 0, 0, 0);\
        o0 = __builtin_amdgcn_mfma_f32_32x32x16_bf16(VF[1], B2_.v, o0, 0, 0, 0);\
        o1 = __builtin_amdgcn_mfma_f32_32x32x16_bf16(VF[2], B1_.v, o1, 0, 0, 0);\
        o1 = __builtin_amdgcn_mfma_f32_32x32x16_bf16(VF[3], B2_.v, o1, 0, 0, 0);\
        __builtin_amdgcn_s_setprio(0);                                          \
    } while (0)

#define ATTN_COMPUTE(QT, QG)                                                    \
    do {                                                                        \
        m = -FLT_MAX; lsum = 0.f;                                               \
        o0 = (f32x16){}; o1 = (f32x16){};                                       \
        _Pragma("unroll")                                                       \
        for (int d = 0; d < 4; ++d)                                             \
            qf[d] = *reinterpret_cast<const bf16x8*>(                           \
                Qh + (size_t)(QG) * HDD + d * 16 + hi * 8);                     \
        bf16x8 kf[4], vf[4];                                                    \
        for (int t = w; t <= (QT); t += 4) {                                    \
            ATTN_LOAD(kf, vf, t);                                               \
            ATTN_TILE(kf, vf, t, t == (QT), QG);                                \
        }                                                                       \
    } while (0)

#define ATTN_WRITE_PARTIALS()                                                   \
    do {                                                                        \
        _Pragma("unroll")                                                       \
        for (int r = 0; r < 16; ++r) {                                          \
            oL[w][lane][r]      = o0[r];                                        \
            oL[w][lane][16 + r] = o1[r];                                        \
        }                                                                       \
        mvL[w][lane] = m;                                                       \
        lvL[w][lane] = lsum;                                                    \
    } while (0)

#define ATTN_MERGE_WRITE(QG)                                                    \
    do {                                                                        \
        float mj[4], lj[4];                                                     \
        _Pragma("unroll")                                                       \
        for (int j = 0; j < 4; ++j) { mj[j] = mvL[j][lane]; lj[j] = lvL[j][lane]; } \
        float mstar = fmaxf(fmaxf(mj[0], mj[1]), fmaxf(mj[2], mj[3]));          \
        float sj[4];                                                            \
        float Lt = 0.f;                                                         \
        _Pragma("unroll")                                                       \
        for (int j = 0; j < 4; ++j) {                                           \
            sj[j] = (lj[j] > 0.f) ? exp2f(mj[j] - mstar) : 0.f;                 \
            Lt += lj[j] * sj[j];                                                \
        }                                                                       \
        const float inv = 1.0f / Lt;                                            \
        __hip_bfloat16* dst = ctx + ((size_t)(b * LLEN + (QG))) * DD + h * HDD; \
        const int T = w >> 1;                                                   \
        const int gb = (w & 1) * 2;                                             \
        _Pragma("unroll")                                                       \
        for (int g2 = 0; g2 < 2; ++g2) {                                        \
            const int g = gb + g2;                                              \
            ushort st4[4];                                                      \
            _Pragma("unroll")                                                   \
            for (int e = 0; e < 4; ++e) {                                       \
                const int r = T * 16 + 4 * g + e;                               \
                float val = oL[0][lane][r] * sj[0] + oL[1][lane][r] * sj[1] +   \
                            oL[2][lane][r] * sj[2] + oL[3][lane][r] * sj[3];    \
                st4[e] = f2bf(val * inv);                                       \
            }                                                                   \
            const int d = T * 32 + 8 * g + 4 * hi;                              \
            *reinterpret_cast<ushort4*>(dst + d) =                              \
                *reinterpret_cast<ushort4*>(st4);                               \
        }                                                                       \
    } while (0)

__global__ __launch_bounds__(256) void attn_mfma5_k(const __bf16* __restrict__ Q,
                                                    const __bf16* __restrict__ K,
                                                    const __bf16* __restrict__ Vt,
                                                    __hip_bfloat16* __restrict__ ctx) {
    __shared__ float oL[4][64][33];
    __shared__ float mvL[4][64];
    __shared__ float lvL[4][64];

    const int tid  = threadIdx.x;
    const int w    = tid >> 6;
    const int lane = tid & 63;
    const int q32  = lane & 31;
    const int hi   = lane >> 5;

    // XCD swizzle: 1024 blocks -> 128-chunk per XCD (4 heads per XCD)
    const int bid = blockIdx.x;
    const int g_  = (bid & 7) * 128 + (bid >> 3);
    const int bh  = g_ >> 5;          // 0..31
    const int ap  = g_ & 31;          // pair index
    const int qtA = 63 - ap;          // heavy qtile
    const int qtB = ap;               // light qtile
    const int qgA = qtA * 32 + q32;
    const int qgB = qtB * 32 + q32;

    const __bf16* Qh = Q  + (size_t)bh * LLEN * HDD;
    const __bf16* Kh = K  + (size_t)bh * LLEN * HDD;
    const __bf16* Vh = Vt + (size_t)bh * HDD * LLEN;

    const __bf16* kbase = Kh + (size_t)q32 * HDD + hi * 8;
    const __bf16* vbase = Vh + (size_t)q32 * LLEN + hi * 8;

    const int b = bh >> 4, h = bh & 15;

    bf16x8 qf[4];
    f32x16 o0, o1;
    float m, lsum;

    // ---- phase A (heavy qtile) ----
    ATTN_COMPUTE(qtA, qgA);
    ATTN_WRITE_PARTIALS();
    __syncthreads();
    ATTN_MERGE_WRITE(qgA);

    // ---- phase B compute overlaps other waves' merge-A reads ----
    ATTN_COMPUTE(qtB, qgB);
    __syncthreads();   // all merge-A LDS reads complete
    ATTN_WRITE_PARTIALS();
    __syncthreads();
    ATTN_MERGE_WRITE(qgB);
}

// ---------------------------------------------------------------------------
extern "C" void kernel_launch(void* const* d_in, const int* in_sizes, int n_in,
                              void* d_out, int out_size, void* d_ws, size_t ws_size,
                              hipStream_t stream) {
    const float* x    = (const float*)d_in[0];
    const float* wq_w = (const float*)d_in[1];
    const float* wq_b = (const float*)d_in[2];
    const float* wk_w = (const float*)d_in[3];
    const float* wk_b = (const float*)d_in[4];
    const float* wv_w = (const float*)d_in[5];
    const float* wv_b = (const float*)d_in[6];
    const float* wo_w = (const float*)d_in[7];
    const float* wo_b = (const float*)d_in[8];
    float* out = (float*)d_out;

    const size_t MB = 1024 * 1024;
    char* p = (char*)d_ws;
    __bf16* x16   = (__bf16*)p;            p += 8 * MB;   // [4096][1024]
    __bf16* wqkvt = (__bf16*)p;            p += 6 * MB;   // [3072][1024]
    __bf16* wot   = (__bf16*)p;            p += 2 * MB;   // [1024][1024]
    __hip_bfloat16* q16  = (__hip_bfloat16*)p; p += 8 * MB;  // [BH][L][HD], pre-scaled by SC2
    __hip_bfloat16* k16  = (__hip_bfloat16*)p; p += 8 * MB;  // [BH][L][HD]
    __hip_bfloat16* v16t = (__hip_bfloat16*)p; p += 8 * MB;  // [BH][HD][L]
    __hip_bfloat16* ctx16 = (__hip_bfloat16*)p;               // [B][L][D]

    hipLaunchKernelGGL(cvt_x_k, dim3(4096), dim3(256), 0, stream, x, (ushort*)x16);
    hipLaunchKernelGGL(wt_cvt_all_k, dim3(16, 16, 4), dim3(256), 0, stream,
                       wq_w, wk_w, wv_w, wo_w, (ushort*)wqkvt, (ushort*)wot);

    // fused QKV projection + RoPE (Q,K) + Q softmax-scale fold + V transpose
    hipLaunchKernelGGL((gemm_mfma_k<1>), dim3(24, 32), dim3(256), 0, stream,
                       x16, wqkvt, wq_b, wk_b, wv_b, (float*)nullptr, q16, k16, v16t);

    // attention (paired-qtile, uniform load)
    hipLaunchKernelGGL(attn_mfma5_k, dim3(1024), dim3(256), 0, stream,
                       (const __bf16*)q16, (const __bf16*)k16, (const __bf16*)v16t, ctx16);

    // output projection
    hipLaunchKernelGGL((gemm_mfma_k<0>), dim3(8, 32), dim3(256), 0, stream,
                       (const __bf16*)ctx16, wot, wo_b, (const float*)nullptr, (const float*)nullptr,
                       out, (__hip_bfloat16*)nullptr, (__hip_bfloat16*)nullptr, (__hip_bfloat16*)nullptr);
}